// Round 1
// baseline (2691.920 us; speedup 1.0000x reference)
//
#include <hip/hip_runtime.h>

typedef __attribute__((ext_vector_type(8))) short short8;
typedef __attribute__((ext_vector_type(4))) float f32x4;
typedef __attribute__((ext_vector_type(8))) unsigned short u16x8;
typedef unsigned short u16;

#define V_SIZE 32000
#define D_MODEL 1024
#define HFF 4096
#define NHEAD 16
#define HDIM 64
#define NLAYER 4
#define BT 4096   // B*T tokens
#define TSEQ 2048

__device__ __forceinline__ u16 f2bf(float f) {
  union { float f; unsigned u; } v; v.f = f;
  unsigned r = v.u + 0x7fffu + ((v.u >> 16) & 1u);
  return (u16)(r >> 16);
}
__device__ __forceinline__ float bf2f(u16 h) {
  union { unsigned u; float f; } v; v.u = ((unsigned)h) << 16;
  return v.f;
}

// ---------------- elementwise / small kernels ----------------

__global__ void rope_table_kernel(float* __restrict__ cosb, float* __restrict__ sinb) {
  int i = blockIdx.x * 256 + threadIdx.x;       // 2048*32 = 65536 items
  int t = i >> 5, fi = i & 31;
  float freq = exp2f(-(2.0f * (float)fi / 64.0f) * log2f(10000.0f));
  float ang = (float)t * freq;
  cosb[i] = cosf(ang);
  sinb[i] = sinf(ang);
}

__global__ void convert_bf16_kernel(const float* __restrict__ src, u16* __restrict__ dst, long n8) {
  long i = (long)blockIdx.x * 256 + threadIdx.x;
  long stride = (long)gridDim.x * 256;
  for (; i < n8; i += stride) {
    const float4* s = (const float4*)(src + i * 8);
    float4 a = s[0], b = s[1];
    u16x8 r;
    r[0] = f2bf(a.x); r[1] = f2bf(a.y); r[2] = f2bf(a.z); r[3] = f2bf(a.w);
    r[4] = f2bf(b.x); r[5] = f2bf(b.y); r[6] = f2bf(b.z); r[7] = f2bf(b.w);
    *(u16x8*)(dst + i * 8) = r;
  }
}

// src [R][C] fp32 -> dst [C][R] bf16
__global__ __launch_bounds__(256) void transpose_bf16_kernel(const float* __restrict__ src,
                                                             u16* __restrict__ dst, int R, int C) {
  __shared__ float tile[32][33];
  int tx = threadIdx.x & 31, ty = threadIdx.x >> 5;  // 32 x 8
  int bx = blockIdx.x, by = blockIdx.y;
#pragma unroll
  for (int i = 0; i < 32; i += 8) {
    int r = by * 32 + ty + i, c = bx * 32 + tx;
    tile[ty + i][tx] = src[(size_t)r * C + c];
  }
  __syncthreads();
#pragma unroll
  for (int i = 0; i < 32; i += 8) {
    int c = bx * 32 + ty + i;   // dst row
    int r = by * 32 + tx;       // dst col
    dst[(size_t)c * R + r] = f2bf(tile[tx][ty + i]);
  }
}

__global__ void embed_gather_kernel(const int* __restrict__ idx, const float* __restrict__ embed,
                                    float* __restrict__ x) {
  int t = blockIdx.x;
  int id = idx[t];
  ((float4*)x)[(size_t)t * 256 + threadIdx.x] = ((const float4*)embed)[(size_t)id * 256 + threadIdx.x];
}

// x fp32 [4096][1024] -> h bf16, h = x * rsqrt(mean(x^2)+eps) * w
__global__ __launch_bounds__(256) void rmsnorm_kernel(const float* __restrict__ x,
                                                      const float* __restrict__ w,
                                                      u16* __restrict__ h) {
  int row = blockIdx.x;
  const float4* xr = (const float4*)(x + (size_t)row * D_MODEL);
  float4 v = xr[threadIdx.x];
  float ss = v.x * v.x + v.y * v.y + v.z * v.z + v.w * v.w;
#pragma unroll
  for (int m = 32; m > 0; m >>= 1) ss += __shfl_xor(ss, m, 64);
  __shared__ float wsum[4];
  if ((threadIdx.x & 63) == 0) wsum[threadIdx.x >> 6] = ss;
  __syncthreads();
  float tot = wsum[0] + wsum[1] + wsum[2] + wsum[3];
  float rinv = rsqrtf(tot * (1.0f / (float)D_MODEL) + 1e-6f);
  float4 wv = ((const float4*)w)[threadIdx.x];
  u16 out[4];
  out[0] = f2bf(v.x * rinv * wv.x);
  out[1] = f2bf(v.y * rinv * wv.y);
  out[2] = f2bf(v.z * rinv * wv.z);
  out[3] = f2bf(v.w * rinv * wv.w);
  u16* hp = h + (size_t)row * D_MODEL + threadIdx.x * 4;
  hp[0] = out[0]; hp[1] = out[1]; hp[2] = out[2]; hp[3] = out[3];
}

// in-place RoPE on q and k (bf16). item = (token, head, pair)
__global__ void rope_apply_kernel(u16* __restrict__ q, u16* __restrict__ k,
                                  const float* __restrict__ cosb, const float* __restrict__ sinb) {
  int i = blockIdx.x * 256 + threadIdx.x;   // 4096*16*32 = 2097152
  int fi = i & 31;
  int h = (i >> 5) & 15;
  int tok = i >> 9;
  int t = tok & (TSEQ - 1);
  float c = cosb[t * 32 + fi], s = sinb[t * 32 + fi];
  size_t base = (size_t)tok * D_MODEL + h * HDIM + fi;
  float q1 = bf2f(q[base]), q2 = bf2f(q[base + 32]);
  q[base] = f2bf(q1 * c - q2 * s);
  q[base + 32] = f2bf(q2 * c + q1 * s);
  float k1 = bf2f(k[base]), k2 = bf2f(k[base + 32]);
  k[base] = f2bf(k1 * c - k2 * s);
  k[base + 32] = f2bf(k2 * c + k1 * s);
}

__global__ void silu_mul_kernel(const u16* __restrict__ g, const u16* __restrict__ u,
                                u16* out) {
  long i = (long)blockIdx.x * 256 + threadIdx.x;   // 16777216/8 items
  short8 gv = *(const short8*)(g + i * 8);
  short8 uv = *(const short8*)(u + i * 8);
  u16x8 r;
#pragma unroll
  for (int j = 0; j < 8; j++) {
    float gf = bf2f((u16)gv[j]);
    float uf = bf2f((u16)uv[j]);
    float sl = gf / (1.0f + expf(-gf));
    r[j] = f2bf(sl * uf);
  }
  *(u16x8*)(out + i * 8) = r;
}

// ---------------- GEMM (NT): C[M,N] = A[M,K](bf16) * B[N,K](bf16)^T ----------------
// EPI: 0 = store fp32, 1 = store bf16, 2 = fp32 residual add (C = resid + acc)
template <int EPI>
__global__ __launch_bounds__(256, 2) void gemm_nt_kernel(const u16* __restrict__ A,
                                                         const u16* __restrict__ B, void* Cp,
                                                         const float* resid, int M, int N, int K) {
  __shared__ u16 As[128 * 64];
  __shared__ u16 Bs[128 * 64];
  const int tid = threadIdx.x;
  const int lane = tid & 63, wid = tid >> 6;
  const int wr = wid >> 1, wc = wid & 1;
  const int bm = blockIdx.y, bn = blockIdx.x;
  const size_t abase = (size_t)bm * 128 * K;
  const size_t bbase = (size_t)bn * 128 * K;
  f32x4 acc[4][4] = {};
  for (int k0 = 0; k0 < K; k0 += 64) {
#pragma unroll
    for (int i = 0; i < 4; i++) {
      int c = tid + 256 * i;
      int row = c >> 3, col = (c & 7) * 8;
      int lidx = row * 64 + (col ^ ((row & 7) << 3));
      short8 va = *(const short8*)(A + abase + (size_t)row * K + k0 + col);
      *(short8*)&As[lidx] = va;
      short8 vb = *(const short8*)(B + bbase + (size_t)row * K + k0 + col);
      *(short8*)&Bs[lidx] = vb;
    }
    __syncthreads();
#pragma unroll
    for (int ks = 0; ks < 2; ks++) {
      short8 af[4], bfr[4];
      int kcol = ks * 32 + (lane >> 4) * 8;
#pragma unroll
      for (int mi = 0; mi < 4; mi++) {
        int r = wr * 64 + mi * 16 + (lane & 15);
        af[mi] = *(const short8*)&As[r * 64 + (kcol ^ ((r & 7) << 3))];
      }
#pragma unroll
      for (int ni = 0; ni < 4; ni++) {
        int r = wc * 64 + ni * 16 + (lane & 15);
        bfr[ni] = *(const short8*)&Bs[r * 64 + (kcol ^ ((r & 7) << 3))];
      }
#pragma unroll
      for (int mi = 0; mi < 4; mi++)
#pragma unroll
        for (int ni = 0; ni < 4; ni++)
          acc[mi][ni] = __builtin_amdgcn_mfma_f32_16x16x32_bf16(af[mi], bfr[ni], acc[mi][ni], 0, 0, 0);
    }
    __syncthreads();
  }
#pragma unroll
  for (int mi = 0; mi < 4; mi++)
#pragma unroll
    for (int ni = 0; ni < 4; ni++)
#pragma unroll
      for (int j = 0; j < 4; j++) {
        int r = bm * 128 + wr * 64 + mi * 16 + (lane >> 4) * 4 + j;
        int cn = bn * 128 + wc * 64 + ni * 16 + (lane & 15);
        size_t off = (size_t)r * N + cn;
        float vv = acc[mi][ni][j];
        if (EPI == 0) ((float*)Cp)[off] = vv;
        else if (EPI == 1) ((u16*)Cp)[off] = f2bf(vv);
        else ((float*)Cp)[off] = resid[off] + vv;
      }
}

// ---------------- flash attention ----------------
// grid: (qtile 0..15, bh 0..31), block 256 (4 waves x 32 q-rows)
__global__ __launch_bounds__(256) void attn_kernel(const u16* __restrict__ q,
                                                   const u16* __restrict__ k,
                                                   const u16* __restrict__ v,
                                                   u16* __restrict__ o) {
  __shared__ u16 Ks[64 * 64];
  __shared__ u16 Vt[64 * 64];
  __shared__ u16 Ps[4][32 * 64];
  const int tid = threadIdx.x, lane = tid & 63, wid = tid >> 6;
  const int qt = blockIdx.x;
  const int bh = blockIdx.y;
  const int b = bh >> 4, h = bh & 15;
  const int tok0 = b * TSEQ;
  const int hoff = h * HDIM;
  const int qrow0 = qt * 128 + wid * 32;

  short8 aq[2][2];
#pragma unroll
  for (int mi = 0; mi < 2; mi++)
#pragma unroll
    for (int ks = 0; ks < 2; ks++) {
      int r = qrow0 + mi * 16 + (lane & 15);
      int d = ks * 32 + (lane >> 4) * 8;
      aq[mi][ks] = *(const short8*)(q + (size_t)(tok0 + r) * D_MODEL + hoff + d);
    }
  f32x4 oacc[2][4] = {};
  float mrow[2][4], lrow[2][4];
#pragma unroll
  for (int mi = 0; mi < 2; mi++)
#pragma unroll
    for (int j = 0; j < 4; j++) { mrow[mi][j] = -1e30f; lrow[mi][j] = 0.f; }

  const int nkt = (qt + 1) * 2;
  for (int kt = 0; kt < nkt; kt++) {
    const int kv0 = kt * 64;
    // stage K [64][64] (swizzled)
#pragma unroll
    for (int i = 0; i < 2; i++) {
      int c = tid + 256 * i;
      int row = c >> 3, col = (c & 7) * 8;
      short8 kv = *(const short8*)(k + (size_t)(tok0 + kv0 + row) * D_MODEL + hoff + col);
      *(short8*)&Ks[row * 64 + (col ^ ((row & 7) << 3))] = kv;
    }
    // stage V^T: Vt[d][t] (swizzled)
    {
      int d = tid & 63, t4 = (tid >> 6) * 8;
#pragma unroll
      for (int half = 0; half < 2; half++) {
        int t0 = t4 + half * 32;
        short8 pk;
#pragma unroll
        for (int jj = 0; jj < 8; jj++)
          pk[jj] = (short)v[(size_t)(tok0 + kv0 + t0 + jj) * D_MODEL + hoff + d];
        *(short8*)&Vt[d * 64 + (t0 ^ ((d & 7) << 3))] = pk;
      }
    }
    __syncthreads();
    // scores: S[q, kcol] = Q . K
    f32x4 sc[2][4] = {};
#pragma unroll
    for (int ks = 0; ks < 2; ks++) {
      short8 bk[4];
      int kcol = ks * 32 + (lane >> 4) * 8;
#pragma unroll
      for (int ni = 0; ni < 4; ni++) {
        int r = ni * 16 + (lane & 15);
        bk[ni] = *(const short8*)&Ks[r * 64 + (kcol ^ ((r & 7) << 3))];
      }
#pragma unroll
      for (int mi = 0; mi < 2; mi++)
#pragma unroll
        for (int ni = 0; ni < 4; ni++)
          sc[mi][ni] = __builtin_amdgcn_mfma_f32_16x16x32_bf16(aq[mi][ks], bk[ni], sc[mi][ni], 0, 0, 0);
    }
    // scale + causal mask + row max
    float pm[2][4];
#pragma unroll
    for (int mi = 0; mi < 2; mi++)
#pragma unroll
      for (int j = 0; j < 4; j++) pm[mi][j] = -1e30f;
#pragma unroll
    for (int mi = 0; mi < 2; mi++)
#pragma unroll
      for (int ni = 0; ni < 4; ni++)
#pragma unroll
        for (int j = 0; j < 4; j++) {
          int rq = qrow0 + mi * 16 + (lane >> 4) * 4 + j;
          int ck = kv0 + ni * 16 + (lane & 15);
          float s = sc[mi][ni][j] * 0.125f;
          if (ck > rq) s = -1e30f;
          sc[mi][ni][j] = s;
          pm[mi][j] = fmaxf(pm[mi][j], s);
        }
#pragma unroll
    for (int mi = 0; mi < 2; mi++)
#pragma unroll
      for (int j = 0; j < 4; j++) {
        float t = pm[mi][j];
        t = fmaxf(t, __shfl_xor(t, 1, 64));
        t = fmaxf(t, __shfl_xor(t, 2, 64));
        t = fmaxf(t, __shfl_xor(t, 4, 64));
        t = fmaxf(t, __shfl_xor(t, 8, 64));
        pm[mi][j] = t;
      }
    // online-softmax update
#pragma unroll
    for (int mi = 0; mi < 2; mi++)
#pragma unroll
      for (int j = 0; j < 4; j++) {
        float mn = fmaxf(mrow[mi][j], pm[mi][j]);
        float fac = expf(mrow[mi][j] - mn);
        lrow[mi][j] *= fac;
#pragma unroll
        for (int df = 0; df < 4; df++) oacc[mi][df][j] *= fac;
        mrow[mi][j] = mn;
      }
    float psum[2][4] = {};
#pragma unroll
    for (int mi = 0; mi < 2; mi++)
#pragma unroll
      for (int ni = 0; ni < 4; ni++)
#pragma unroll
        for (int j = 0; j < 4; j++) {
          float p = expf(sc[mi][ni][j] - mrow[mi][j]);
          psum[mi][j] += p;
          int r32 = mi * 16 + (lane >> 4) * 4 + j;
          int cc = ni * 16 + (lane & 15);
          Ps[wid][r32 * 64 + (cc ^ ((r32 & 7) << 3))] = f2bf(p);
        }
#pragma unroll
    for (int mi = 0; mi < 2; mi++)
#pragma unroll
      for (int j = 0; j < 4; j++) {
        float t = psum[mi][j];
        t += __shfl_xor(t, 1, 64);
        t += __shfl_xor(t, 2, 64);
        t += __shfl_xor(t, 4, 64);
        t += __shfl_xor(t, 8, 64);
        lrow[mi][j] += t;
      }
    // PV: O += P[32,64] * V[64,64]
#pragma unroll
    for (int kf = 0; kf < 2; kf++) {
      short8 pa[2], bv[4];
      int kcol = kf * 32 + (lane >> 4) * 8;
#pragma unroll
      for (int mi = 0; mi < 2; mi++) {
        int r = mi * 16 + (lane & 15);
        pa[mi] = *(const short8*)&Ps[wid][r * 64 + (kcol ^ ((r & 7) << 3))];
      }
#pragma unroll
      for (int df = 0; df < 4; df++) {
        int r = df * 16 + (lane & 15);
        bv[df] = *(const short8*)&Vt[r * 64 + (kcol ^ ((r & 7) << 3))];
      }
#pragma unroll
      for (int mi = 0; mi < 2; mi++)
#pragma unroll
        for (int df = 0; df < 4; df++)
          oacc[mi][df] = __builtin_amdgcn_mfma_f32_16x16x32_bf16(pa[mi], bv[df], oacc[mi][df], 0, 0, 0);
    }
    __syncthreads();
  }
  // finalize
#pragma unroll
  for (int mi = 0; mi < 2; mi++)
#pragma unroll
    for (int df = 0; df < 4; df++)
#pragma unroll
      for (int j = 0; j < 4; j++) {
        int r = qrow0 + mi * 16 + (lane >> 4) * 4 + j;
        int d = df * 16 + (lane & 15);
        float val = oacc[mi][df][j] / lrow[mi][j];
        o[(size_t)(tok0 + r) * D_MODEL + hoff + d] = f2bf(val);
      }
}

// ---------------- loss ----------------

__global__ __launch_bounds__(256) void nll_kernel(const float* __restrict__ logits,
                                                  const int* __restrict__ targets,
                                                  float* __restrict__ nll) {
  int tok = blockIdx.x;
  const float* row = logits + (size_t)tok * V_SIZE;
  float m = -1e30f, s = 0.f;
  for (int j = threadIdx.x; j < V_SIZE; j += 256) {
    float v0 = row[j];
    float nm = fmaxf(m, v0);
    s = s * expf(m - nm) + expf(v0 - nm);
    m = nm;
  }
#pragma unroll
  for (int mask = 1; mask < 64; mask <<= 1) {
    float m2 = __shfl_xor(m, mask, 64);
    float s2 = __shfl_xor(s, mask, 64);
    float nm = fmaxf(m, m2);
    s = s * expf(m - nm) + s2 * expf(m2 - nm);
    m = nm;
  }
  __shared__ float sm[4], ssum[4];
  int wid = threadIdx.x >> 6;
  if ((threadIdx.x & 63) == 0) { sm[wid] = m; ssum[wid] = s; }
  __syncthreads();
  if (threadIdx.x == 0) {
    float M = sm[0], S = ssum[0];
    for (int w = 1; w < 4; w++) {
      float nm = fmaxf(M, sm[w]);
      S = S * expf(M - nm) + ssum[w] * expf(sm[w] - nm);
      M = nm;
    }
    float lse = M + logf(S);
    nll[tok] = lse - row[targets[tok]];
  }
}

__global__ void loss_reduce_kernel(const float* __restrict__ nll, float* __restrict__ out) {
  float s = 0.f;
  for (int i = threadIdx.x; i < BT; i += 256) s += nll[i];
#pragma unroll
  for (int mask = 1; mask < 64; mask <<= 1) s += __shfl_xor(s, mask, 64);
  __shared__ float sm[4];
  if ((threadIdx.x & 63) == 0) sm[threadIdx.x >> 6] = s;
  __syncthreads();
  if (threadIdx.x == 0) out[0] = (sm[0] + sm[1] + sm[2] + sm[3]) / (float)BT;
}

// ---------------- host launcher ----------------

extern "C" void kernel_launch(void* const* d_in, const int* in_sizes, int n_in,
                              void* d_out, int out_size, void* d_ws, size_t ws_size,
                              hipStream_t stream) {
  const int* idx = (const int*)d_in[0];
  const int* targets = (const int*)d_in[1];
  const float* embed = (const float*)d_in[2];
  const float* wq = (const float*)d_in[3];
  const float* wk = (const float*)d_in[4];
  const float* wv = (const float*)d_in[5];
  const float* wo = (const float*)d_in[6];
  const float* w_gate = (const float*)d_in[7];
  const float* w_up = (const float*)d_in[8];
  const float* w_down = (const float*)d_in[9];
  const float* attn_norm = (const float*)d_in[10];
  const float* mlp_norm = (const float*)d_in[11];
  const float* final_norm = (const float*)d_in[12];
  const float* lm_head = (const float*)d_in[13];
  float* out = (float*)d_out;

  char* ws = (char*)d_ws;
  size_t off = 0;
  auto alloc = [&](size_t bytes) {
    void* p = ws + off;
    off += (bytes + 255) & ~(size_t)255;
    return p;
  };
  float* rope_cos = (float*)alloc((size_t)TSEQ * 32 * 4);
  float* rope_sin = (float*)alloc((size_t)TSEQ * 32 * 4);
  float* X = (float*)alloc((size_t)BT * D_MODEL * 4);
  u16* Hb = (u16*)alloc((size_t)BT * D_MODEL * 2);
  u16* Qb = (u16*)alloc((size_t)BT * D_MODEL * 2);
  u16* Kb = (u16*)alloc((size_t)BT * D_MODEL * 2);
  u16* Vb = (u16*)alloc((size_t)BT * D_MODEL * 2);
  u16* Ob = (u16*)alloc((size_t)BT * D_MODEL * 2);
  u16* Gb = (u16*)alloc((size_t)BT * HFF * 2);
  u16* Ub = (u16*)alloc((size_t)BT * HFF * 2);
  u16* WQT = (u16*)alloc((size_t)D_MODEL * D_MODEL * 2);
  u16* WKT = (u16*)alloc((size_t)D_MODEL * D_MODEL * 2);
  u16* WVT = (u16*)alloc((size_t)D_MODEL * D_MODEL * 2);
  u16* WOT = (u16*)alloc((size_t)D_MODEL * D_MODEL * 2);
  u16* WGT = (u16*)alloc((size_t)HFF * D_MODEL * 2);
  u16* WUT = (u16*)alloc((size_t)HFF * D_MODEL * 2);
  u16* WDT = (u16*)alloc((size_t)D_MODEL * HFF * 2);
  u16* LMH = (u16*)alloc((size_t)V_SIZE * D_MODEL * 2);
  float* NLLb = (float*)alloc((size_t)BT * 4);

  rope_table_kernel<<<256, 256, 0, stream>>>(rope_cos, rope_sin);
  convert_bf16_kernel<<<4096, 256, 0, stream>>>(lm_head, LMH, (long)V_SIZE * D_MODEL / 8);
  embed_gather_kernel<<<4096, 256, 0, stream>>>(idx, embed, X);

  for (int l = 0; l < NLAYER; l++) {
    const float* wq_l = wq + (size_t)l * D_MODEL * D_MODEL;
    const float* wk_l = wk + (size_t)l * D_MODEL * D_MODEL;
    const float* wv_l = wv + (size_t)l * D_MODEL * D_MODEL;
    const float* wo_l = wo + (size_t)l * D_MODEL * D_MODEL;
    const float* wg_l = w_gate + (size_t)l * D_MODEL * HFF;
    const float* wu_l = w_up + (size_t)l * D_MODEL * HFF;
    const float* wd_l = w_down + (size_t)l * HFF * D_MODEL;

    transpose_bf16_kernel<<<dim3(32, 32), 256, 0, stream>>>(wq_l, WQT, D_MODEL, D_MODEL);
    transpose_bf16_kernel<<<dim3(32, 32), 256, 0, stream>>>(wk_l, WKT, D_MODEL, D_MODEL);
    transpose_bf16_kernel<<<dim3(32, 32), 256, 0, stream>>>(wv_l, WVT, D_MODEL, D_MODEL);
    transpose_bf16_kernel<<<dim3(32, 32), 256, 0, stream>>>(wo_l, WOT, D_MODEL, D_MODEL);
    transpose_bf16_kernel<<<dim3(128, 32), 256, 0, stream>>>(wg_l, WGT, D_MODEL, HFF);
    transpose_bf16_kernel<<<dim3(128, 32), 256, 0, stream>>>(wu_l, WUT, D_MODEL, HFF);
    transpose_bf16_kernel<<<dim3(32, 128), 256, 0, stream>>>(wd_l, WDT, HFF, D_MODEL);

    rmsnorm_kernel<<<BT, 256, 0, stream>>>(X, attn_norm + (size_t)l * D_MODEL, Hb);
    gemm_nt_kernel<1><<<dim3(8, 32), 256, 0, stream>>>(Hb, WQT, Qb, nullptr, BT, D_MODEL, D_MODEL);
    gemm_nt_kernel<1><<<dim3(8, 32), 256, 0, stream>>>(Hb, WKT, Kb, nullptr, BT, D_MODEL, D_MODEL);
    gemm_nt_kernel<1><<<dim3(8, 32), 256, 0, stream>>>(Hb, WVT, Vb, nullptr, BT, D_MODEL, D_MODEL);
    rope_apply_kernel<<<8192, 256, 0, stream>>>(Qb, Kb, rope_cos, rope_sin);
    attn_kernel<<<dim3(16, 32), 256, 0, stream>>>(Qb, Kb, Vb, Ob);
    gemm_nt_kernel<2><<<dim3(8, 32), 256, 0, stream>>>(Ob, WOT, X, X, BT, D_MODEL, D_MODEL);

    rmsnorm_kernel<<<BT, 256, 0, stream>>>(X, mlp_norm + (size_t)l * D_MODEL, Hb);
    gemm_nt_kernel<1><<<dim3(32, 32), 256, 0, stream>>>(Hb, WGT, Gb, nullptr, BT, HFF, D_MODEL);
    gemm_nt_kernel<1><<<dim3(32, 32), 256, 0, stream>>>(Hb, WUT, Ub, nullptr, BT, HFF, D_MODEL);
    silu_mul_kernel<<<8192, 256, 0, stream>>>(Gb, Ub, Gb);
    gemm_nt_kernel<2><<<dim3(8, 32), 256, 0, stream>>>(Gb, WDT, X, X, BT, D_MODEL, HFF);
  }

  rmsnorm_kernel<<<BT, 256, 0, stream>>>(X, final_norm, Hb);
  gemm_nt_kernel<0><<<dim3(250, 32), 256, 0, stream>>>(Hb, LMH, out, nullptr, BT, V_SIZE, D_MODEL);
  nll_kernel<<<BT, 256, 0, stream>>>(out, targets, NLLb);
  loss_reduce_kernel<<<1, 256, 0, stream>>>(NLLb, out + (size_t)BT * V_SIZE);
}

// Round 2
// 2545.606 us; speedup vs baseline: 1.0575x; 1.0575x over previous
//
#include <hip/hip_runtime.h>

typedef __attribute__((ext_vector_type(8))) short short8;
typedef __attribute__((ext_vector_type(4))) float f32x4;
typedef __attribute__((ext_vector_type(8))) unsigned short u16x8;
typedef unsigned short u16;

#define V_SIZE 32000
#define D_MODEL 1024
#define HFF 4096
#define NHEAD 16
#define HDIM 64
#define NLAYER 4
#define BT 4096   // B*T tokens
#define TSEQ 2048
#define QKV_STRIDE 3072
#define GU_STRIDE 8192

__device__ __forceinline__ u16 f2bf(float f) {
  union { float f; unsigned u; } v; v.f = f;
  unsigned r = v.u + 0x7fffu + ((v.u >> 16) & 1u);
  return (u16)(r >> 16);
}
__device__ __forceinline__ float bf2f(u16 h) {
  union { unsigned u; float f; } v; v.u = ((unsigned)h) << 16;
  return v.f;
}

__device__ __forceinline__ void gload_lds16(const void* g, void* l) {
  __builtin_amdgcn_global_load_lds((__attribute__((address_space(1))) void*)g,
                                   (__attribute__((address_space(3))) void*)l, 16, 0, 0);
}

// ---------------- elementwise / small kernels ----------------

__global__ void rope_table_kernel(float* __restrict__ cosb, float* __restrict__ sinb) {
  int i = blockIdx.x * 256 + threadIdx.x;       // 2048*32 = 65536 items
  int t = i >> 5, fi = i & 31;
  float freq = exp2f(-(2.0f * (float)fi / 64.0f) * log2f(10000.0f));
  float ang = (float)t * freq;
  cosb[i] = cosf(ang);
  sinb[i] = sinf(ang);
}

__global__ void convert_bf16_kernel(const float* __restrict__ src, u16* __restrict__ dst, long n8) {
  long i = (long)blockIdx.x * 256 + threadIdx.x;
  long stride = (long)gridDim.x * 256;
  for (; i < n8; i += stride) {
    const float4* s = (const float4*)(src + i * 8);
    float4 a = s[0], b = s[1];
    u16x8 r;
    r[0] = f2bf(a.x); r[1] = f2bf(a.y); r[2] = f2bf(a.z); r[3] = f2bf(a.w);
    r[4] = f2bf(b.x); r[5] = f2bf(b.y); r[6] = f2bf(b.z); r[7] = f2bf(b.w);
    *(u16x8*)(dst + i * 8) = r;
  }
}

// src [R][C] fp32 -> dst [C][R] bf16, batched over blockIdx.z
__global__ __launch_bounds__(256) void transpose_bf16_kernel(const float* __restrict__ src0,
                                                             u16* __restrict__ dst0, int R, int C,
                                                             long srcStride, long dstStride) {
  __shared__ float tile[32][33];
  const float* src = src0 + (size_t)blockIdx.z * srcStride;
  u16* dst = dst0 + (size_t)blockIdx.z * dstStride;
  int tx = threadIdx.x & 31, ty = threadIdx.x >> 5;  // 32 x 8
  int bx = blockIdx.x, by = blockIdx.y;
#pragma unroll
  for (int i = 0; i < 32; i += 8) {
    int r = by * 32 + ty + i, c = bx * 32 + tx;
    tile[ty + i][tx] = src[(size_t)r * C + c];
  }
  __syncthreads();
#pragma unroll
  for (int i = 0; i < 32; i += 8) {
    int c = bx * 32 + ty + i;   // dst row
    int r = by * 32 + tx;       // dst col
    dst[(size_t)c * R + r] = f2bf(tile[tx][ty + i]);
  }
}

__global__ void embed_gather_kernel(const int* __restrict__ idx, const float* __restrict__ embed,
                                    float* __restrict__ x) {
  int t = blockIdx.x;
  int id = idx[t];
  ((float4*)x)[(size_t)t * 256 + threadIdx.x] = ((const float4*)embed)[(size_t)id * 256 + threadIdx.x];
}

// x fp32 [4096][1024] -> h bf16, h = x * rsqrt(mean(x^2)+eps) * w
__global__ __launch_bounds__(256) void rmsnorm_kernel(const float* __restrict__ x,
                                                      const float* __restrict__ w,
                                                      u16* __restrict__ h) {
  int row = blockIdx.x;
  const float4* xr = (const float4*)(x + (size_t)row * D_MODEL);
  float4 v = xr[threadIdx.x];
  float ss = v.x * v.x + v.y * v.y + v.z * v.z + v.w * v.w;
#pragma unroll
  for (int m = 32; m > 0; m >>= 1) ss += __shfl_xor(ss, m, 64);
  __shared__ float wsum[4];
  if ((threadIdx.x & 63) == 0) wsum[threadIdx.x >> 6] = ss;
  __syncthreads();
  float tot = wsum[0] + wsum[1] + wsum[2] + wsum[3];
  float rinv = rsqrtf(tot * (1.0f / (float)D_MODEL) + 1e-6f);
  float4 wv = ((const float4*)w)[threadIdx.x];
  u16 out[4];
  out[0] = f2bf(v.x * rinv * wv.x);
  out[1] = f2bf(v.y * rinv * wv.y);
  out[2] = f2bf(v.z * rinv * wv.z);
  out[3] = f2bf(v.w * rinv * wv.w);
  u16* hp = h + (size_t)row * D_MODEL + threadIdx.x * 4;
  hp[0] = out[0]; hp[1] = out[1]; hp[2] = out[2]; hp[3] = out[3];
}

// in-place RoPE on q and k inside the fused QKV buffer (row stride 3072)
__global__ void rope_apply_kernel(u16* __restrict__ qkv,
                                  const float* __restrict__ cosb, const float* __restrict__ sinb) {
  int i = blockIdx.x * 256 + threadIdx.x;   // 4096*16*32 = 2097152
  int fi = i & 31;
  int h = (i >> 5) & 15;
  int tok = i >> 9;
  int t = tok & (TSEQ - 1);
  float c = cosb[t * 32 + fi], s = sinb[t * 32 + fi];
  size_t base = (size_t)tok * QKV_STRIDE + h * HDIM + fi;
  float q1 = bf2f(qkv[base]), q2 = bf2f(qkv[base + 32]);
  qkv[base] = f2bf(q1 * c - q2 * s);
  qkv[base + 32] = f2bf(q2 * c + q1 * s);
  size_t kb = base + D_MODEL;
  float k1 = bf2f(qkv[kb]), k2 = bf2f(qkv[kb + 32]);
  qkv[kb] = f2bf(k1 * c - k2 * s);
  qkv[kb + 32] = f2bf(k2 * c + k1 * s);
}

// gu [4096][8192] (gate | up) -> out [4096][4096] = silu(gate)*up
__global__ void silu_mul_kernel(const u16* __restrict__ gu, u16* __restrict__ out) {
  long i = (long)blockIdx.x * 256 + threadIdx.x;   // 4096*4096/8 items
  int tok = (int)(i >> 9);
  int col = ((int)i & 511) * 8;
  short8 gv = *(const short8*)(gu + (size_t)tok * GU_STRIDE + col);
  short8 uv = *(const short8*)(gu + (size_t)tok * GU_STRIDE + HFF + col);
  u16x8 r;
#pragma unroll
  for (int j = 0; j < 8; j++) {
    float gf = bf2f((u16)gv[j]);
    float uf = bf2f((u16)uv[j]);
    float sl = gf / (1.0f + expf(-gf));
    r[j] = f2bf(sl * uf);
  }
  *(u16x8*)(out + (size_t)tok * HFF + col) = r;
}

// ---------------- GEMM (NT, m97 structure): C[M,N] = A[M,K](bf16) * B[N,K](bf16)^T ----------------
// global_load_lds width-16 staging into LINEAR LDS, 2-barrier loop, XCD-swizzled 1D grid.
// EPI: 0 = store fp32, 1 = store bf16, 2 = fp32 residual add (C = resid + acc)
template <int EPI>
__global__ __launch_bounds__(256, 2) void gemm_nt_kernel(const u16* __restrict__ A,
                                                         const u16* __restrict__ B, void* Cp,
                                                         const float* resid, int M, int N, int K) {
  __shared__ u16 As[128 * 64];
  __shared__ u16 Bs[128 * 64];
  const int tid = threadIdx.x;
  const int lane = tid & 63, wid = tid >> 6;
  const int wr = wid >> 1, wc = wid & 1;
  // bijective XCD swizzle (nwg divisible by 8 for all our launches)
  const int nbx = N >> 7;
  const int cpx = gridDim.x >> 3;
  const int swz = (blockIdx.x & 7) * cpx + (blockIdx.x >> 3);
  const int bm = swz / nbx, bn = swz - bm * nbx;
  const size_t abase = (size_t)bm * 128 * K;
  const size_t bbase = (size_t)bn * 128 * K;
  f32x4 acc[4][4] = {};
  for (int k0 = 0; k0 < K; k0 += 64) {
#pragma unroll
    for (int i = 0; i < 4; i++) {
      int idx8 = i * 256 + tid;
      int row = idx8 >> 3, col = (idx8 & 7) << 3;
      gload_lds16(A + abase + (size_t)row * K + k0 + col, As + idx8 * 8);
      gload_lds16(B + bbase + (size_t)row * K + k0 + col, Bs + idx8 * 8);
    }
    __syncthreads();
#pragma unroll
    for (int ks = 0; ks < 2; ks++) {
      short8 af[4], bfr[4];
      int kcol = ks * 32 + (lane >> 4) * 8;
#pragma unroll
      for (int mi = 0; mi < 4; mi++)
        af[mi] = *(const short8*)&As[(wr * 64 + mi * 16 + (lane & 15)) * 64 + kcol];
#pragma unroll
      for (int ni = 0; ni < 4; ni++)
        bfr[ni] = *(const short8*)&Bs[(wc * 64 + ni * 16 + (lane & 15)) * 64 + kcol];
#pragma unroll
      for (int mi = 0; mi < 4; mi++)
#pragma unroll
        for (int ni = 0; ni < 4; ni++)
          acc[mi][ni] = __builtin_amdgcn_mfma_f32_16x16x32_bf16(af[mi], bfr[ni], acc[mi][ni], 0, 0, 0);
    }
    __syncthreads();
  }
#pragma unroll
  for (int mi = 0; mi < 4; mi++)
#pragma unroll
    for (int ni = 0; ni < 4; ni++)
#pragma unroll
      for (int j = 0; j < 4; j++) {
        int r = bm * 128 + wr * 64 + mi * 16 + (lane >> 4) * 4 + j;
        int cn = bn * 128 + wc * 64 + ni * 16 + (lane & 15);
        size_t off = (size_t)r * N + cn;
        float vv = acc[mi][ni][j];
        if (EPI == 0) ((float*)Cp)[off] = vv;
        else if (EPI == 1) ((u16*)Cp)[off] = f2bf(vv);
        else ((float*)Cp)[off] = resid[off] + vv;
      }
}

// ---------------- flash attention ----------------
// q/k/v live in the fused QKV buffer (row stride 3072, offsets 0/1024/2048).
// grid: (qtile 0..15, bh 0..31), block 256 (4 waves x 32 q-rows)
__global__ __launch_bounds__(256) void attn_kernel(const u16* __restrict__ qkv,
                                                   u16* __restrict__ o) {
  __shared__ u16 Ks[64 * 64];
  __shared__ u16 Vt[64 * 64];
  __shared__ u16 Ps[4][32 * 64];
  const u16* q = qkv;
  const u16* k = qkv + D_MODEL;
  const u16* v = qkv + 2 * D_MODEL;
  const int tid = threadIdx.x, lane = tid & 63, wid = tid >> 6;
  const int qt = blockIdx.x;
  const int bh = blockIdx.y;
  const int b = bh >> 4, h = bh & 15;
  const int tok0 = b * TSEQ;
  const int hoff = h * HDIM;
  const int qrow0 = qt * 128 + wid * 32;

  short8 aq[2][2];
#pragma unroll
  for (int mi = 0; mi < 2; mi++)
#pragma unroll
    for (int ks = 0; ks < 2; ks++) {
      int r = qrow0 + mi * 16 + (lane & 15);
      int d = ks * 32 + (lane >> 4) * 8;
      aq[mi][ks] = *(const short8*)(q + (size_t)(tok0 + r) * QKV_STRIDE + hoff + d);
    }
  f32x4 oacc[2][4] = {};
  float mrow[2][4], lrow[2][4];
#pragma unroll
  for (int mi = 0; mi < 2; mi++)
#pragma unroll
    for (int j = 0; j < 4; j++) { mrow[mi][j] = -1e30f; lrow[mi][j] = 0.f; }

  const int nkt = (qt + 1) * 2;
  for (int kt = 0; kt < nkt; kt++) {
    const int kv0 = kt * 64;
    // stage K [64][64] (swizzled)
#pragma unroll
    for (int i = 0; i < 2; i++) {
      int c = tid + 256 * i;
      int row = c >> 3, col = (c & 7) * 8;
      short8 kv = *(const short8*)(k + (size_t)(tok0 + kv0 + row) * QKV_STRIDE + hoff + col);
      *(short8*)&Ks[row * 64 + (col ^ ((row & 7) << 3))] = kv;
    }
    // stage V^T: Vt[d][t] (swizzled)
    {
      int d = tid & 63, t4 = (tid >> 6) * 8;
#pragma unroll
      for (int half = 0; half < 2; half++) {
        int t0 = t4 + half * 32;
        short8 pk;
#pragma unroll
        for (int jj = 0; jj < 8; jj++)
          pk[jj] = (short)v[(size_t)(tok0 + kv0 + t0 + jj) * QKV_STRIDE + hoff + d];
        *(short8*)&Vt[d * 64 + (t0 ^ ((d & 7) << 3))] = pk;
      }
    }
    __syncthreads();
    // scores: S[q, kcol] = Q . K
    f32x4 sc[2][4] = {};
#pragma unroll
    for (int ks = 0; ks < 2; ks++) {
      short8 bk[4];
      int kcol = ks * 32 + (lane >> 4) * 8;
#pragma unroll
      for (int ni = 0; ni < 4; ni++) {
        int r = ni * 16 + (lane & 15);
        bk[ni] = *(const short8*)&Ks[r * 64 + (kcol ^ ((r & 7) << 3))];
      }
#pragma unroll
      for (int mi = 0; mi < 2; mi++)
#pragma unroll
        for (int ni = 0; ni < 4; ni++)
          sc[mi][ni] = __builtin_amdgcn_mfma_f32_16x16x32_bf16(aq[mi][ks], bk[ni], sc[mi][ni], 0, 0, 0);
    }
    // scale + causal mask + row max
    float pm[2][4];
#pragma unroll
    for (int mi = 0; mi < 2; mi++)
#pragma unroll
      for (int j = 0; j < 4; j++) pm[mi][j] = -1e30f;
#pragma unroll
    for (int mi = 0; mi < 2; mi++)
#pragma unroll
      for (int ni = 0; ni < 4; ni++)
#pragma unroll
        for (int j = 0; j < 4; j++) {
          int rq = qrow0 + mi * 16 + (lane >> 4) * 4 + j;
          int ck = kv0 + ni * 16 + (lane & 15);
          float s = sc[mi][ni][j] * 0.125f;
          if (ck > rq) s = -1e30f;
          sc[mi][ni][j] = s;
          pm[mi][j] = fmaxf(pm[mi][j], s);
        }
#pragma unroll
    for (int mi = 0; mi < 2; mi++)
#pragma unroll
      for (int j = 0; j < 4; j++) {
        float t = pm[mi][j];
        t = fmaxf(t, __shfl_xor(t, 1, 64));
        t = fmaxf(t, __shfl_xor(t, 2, 64));
        t = fmaxf(t, __shfl_xor(t, 4, 64));
        t = fmaxf(t, __shfl_xor(t, 8, 64));
        pm[mi][j] = t;
      }
    // online-softmax update
#pragma unroll
    for (int mi = 0; mi < 2; mi++)
#pragma unroll
      for (int j = 0; j < 4; j++) {
        float mn = fmaxf(mrow[mi][j], pm[mi][j]);
        float fac = expf(mrow[mi][j] - mn);
        lrow[mi][j] *= fac;
#pragma unroll
        for (int df = 0; df < 4; df++) oacc[mi][df][j] *= fac;
        mrow[mi][j] = mn;
      }
    float psum[2][4] = {};
#pragma unroll
    for (int mi = 0; mi < 2; mi++)
#pragma unroll
      for (int ni = 0; ni < 4; ni++)
#pragma unroll
        for (int j = 0; j < 4; j++) {
          float p = expf(sc[mi][ni][j] - mrow[mi][j]);
          psum[mi][j] += p;
          int r32 = mi * 16 + (lane >> 4) * 4 + j;
          int cc = ni * 16 + (lane & 15);
          Ps[wid][r32 * 64 + (cc ^ ((r32 & 7) << 3))] = f2bf(p);
        }
#pragma unroll
    for (int mi = 0; mi < 2; mi++)
#pragma unroll
      for (int j = 0; j < 4; j++) {
        float t = psum[mi][j];
        t += __shfl_xor(t, 1, 64);
        t += __shfl_xor(t, 2, 64);
        t += __shfl_xor(t, 4, 64);
        t += __shfl_xor(t, 8, 64);
        lrow[mi][j] += t;
      }
    // PV: O += P[32,64] * V[64,64]
#pragma unroll
    for (int kf = 0; kf < 2; kf++) {
      short8 pa[2], bv[4];
      int kcol = kf * 32 + (lane >> 4) * 8;
#pragma unroll
      for (int mi = 0; mi < 2; mi++) {
        int r = mi * 16 + (lane & 15);
        pa[mi] = *(const short8*)&Ps[wid][r * 64 + (kcol ^ ((r & 7) << 3))];
      }
#pragma unroll
      for (int df = 0; df < 4; df++) {
        int r = df * 16 + (lane & 15);
        bv[df] = *(const short8*)&Vt[r * 64 + (kcol ^ ((r & 7) << 3))];
      }
#pragma unroll
      for (int mi = 0; mi < 2; mi++)
#pragma unroll
        for (int df = 0; df < 4; df++)
          oacc[mi][df] = __builtin_amdgcn_mfma_f32_16x16x32_bf16(pa[mi], bv[df], oacc[mi][df], 0, 0, 0);
    }
    __syncthreads();
  }
  // finalize
#pragma unroll
  for (int mi = 0; mi < 2; mi++)
#pragma unroll
    for (int df = 0; df < 4; df++)
#pragma unroll
      for (int j = 0; j < 4; j++) {
        int r = qrow0 + mi * 16 + (lane >> 4) * 4 + j;
        int d = df * 16 + (lane & 15);
        float val = oacc[mi][df][j] / lrow[mi][j];
        o[(size_t)(tok0 + r) * D_MODEL + hoff + d] = f2bf(val);
      }
}

// ---------------- loss ----------------

__global__ __launch_bounds__(256) void nll_kernel(const float* __restrict__ logits,
                                                  const int* __restrict__ targets,
                                                  float* __restrict__ nll) {
  int tok = blockIdx.x;
  const float* row = logits + (size_t)tok * V_SIZE;
  const float4* row4 = (const float4*)row;
  float m = -1e30f, s = 0.f;
  for (int j = threadIdx.x; j < V_SIZE / 4; j += 256) {
    float4 v4 = row4[j];
#pragma unroll
    for (int e = 0; e < 4; e++) {
      float v0 = (e == 0) ? v4.x : (e == 1) ? v4.y : (e == 2) ? v4.z : v4.w;
      float nm = fmaxf(m, v0);
      s = s * expf(m - nm) + expf(v0 - nm);
      m = nm;
    }
  }
#pragma unroll
  for (int mask = 1; mask < 64; mask <<= 1) {
    float m2 = __shfl_xor(m, mask, 64);
    float s2 = __shfl_xor(s, mask, 64);
    float nm = fmaxf(m, m2);
    s = s * expf(m - nm) + s2 * expf(m2 - nm);
    m = nm;
  }
  __shared__ float sm[4], ssum[4];
  int wid = threadIdx.x >> 6;
  if ((threadIdx.x & 63) == 0) { sm[wid] = m; ssum[wid] = s; }
  __syncthreads();
  if (threadIdx.x == 0) {
    float M = sm[0], S = ssum[0];
    for (int w = 1; w < 4; w++) {
      float nm = fmaxf(M, sm[w]);
      S = S * expf(M - nm) + ssum[w] * expf(sm[w] - nm);
      M = nm;
    }
    float lse = M + logf(S);
    nll[tok] = lse - row[targets[tok]];
  }
}

__global__ void loss_reduce_kernel(const float* __restrict__ nll, float* __restrict__ out) {
  float s = 0.f;
  for (int i = threadIdx.x; i < BT; i += 256) s += nll[i];
#pragma unroll
  for (int mask = 1; mask < 64; mask <<= 1) s += __shfl_xor(s, mask, 64);
  __shared__ float sm[4];
  if ((threadIdx.x & 63) == 0) sm[threadIdx.x >> 6] = s;
  __syncthreads();
  if (threadIdx.x == 0) out[0] = (sm[0] + sm[1] + sm[2] + sm[3]) / (float)BT;
}

// ---------------- host launcher ----------------

extern "C" void kernel_launch(void* const* d_in, const int* in_sizes, int n_in,
                              void* d_out, int out_size, void* d_ws, size_t ws_size,
                              hipStream_t stream) {
  const int* idx = (const int*)d_in[0];
  const int* targets = (const int*)d_in[1];
  const float* embed = (const float*)d_in[2];
  const float* wq = (const float*)d_in[3];
  const float* wk = (const float*)d_in[4];
  const float* wv = (const float*)d_in[5];
  const float* wo = (const float*)d_in[6];
  const float* w_gate = (const float*)d_in[7];
  const float* w_up = (const float*)d_in[8];
  const float* w_down = (const float*)d_in[9];
  const float* attn_norm = (const float*)d_in[10];
  const float* mlp_norm = (const float*)d_in[11];
  const float* final_norm = (const float*)d_in[12];
  const float* lm_head = (const float*)d_in[13];
  float* out = (float*)d_out;

  char* ws = (char*)d_ws;
  size_t off = 0;
  auto alloc = [&](size_t bytes) {
    void* p = ws + off;
    off += (bytes + 255) & ~(size_t)255;
    return p;
  };
  const size_t DD = (size_t)D_MODEL * D_MODEL;
  float* rope_cos = (float*)alloc((size_t)TSEQ * 32 * 4);
  float* rope_sin = (float*)alloc((size_t)TSEQ * 32 * 4);
  float* X = (float*)alloc((size_t)BT * D_MODEL * 4);
  u16* Hb = (u16*)alloc((size_t)BT * D_MODEL * 2);
  u16* QKVb = (u16*)alloc((size_t)BT * QKV_STRIDE * 2);
  u16* Ob = (u16*)alloc((size_t)BT * D_MODEL * 2);
  u16* GUb = (u16*)alloc((size_t)BT * GU_STRIDE * 2);
  u16* Gb = (u16*)alloc((size_t)BT * HFF * 2);
  u16* WQKVT = (u16*)alloc((size_t)NLAYER * QKV_STRIDE * D_MODEL * 2);
  u16* WOT = (u16*)alloc((size_t)NLAYER * DD * 2);
  u16* WGU = (u16*)alloc((size_t)NLAYER * GU_STRIDE * D_MODEL * 2);
  u16* WDT = (u16*)alloc((size_t)NLAYER * D_MODEL * HFF * 2);
  u16* LMH = (u16*)alloc((size_t)V_SIZE * D_MODEL * 2);
  float* NLLb = (float*)alloc((size_t)BT * 4);

  rope_table_kernel<<<256, 256, 0, stream>>>(rope_cos, rope_sin);
  convert_bf16_kernel<<<4096, 256, 0, stream>>>(lm_head, LMH, (long)V_SIZE * D_MODEL / 8);
  embed_gather_kernel<<<BT, 256, 0, stream>>>(idx, embed, X);

  // batched weight transposes (all layers in one launch per weight type)
  const long QKVW = (long)QKV_STRIDE * D_MODEL;
  const long GUW = (long)GU_STRIDE * D_MODEL;
  const long DW = (long)D_MODEL * HFF;
  transpose_bf16_kernel<<<dim3(32, 32, NLAYER), 256, 0, stream>>>(wq, WQKVT, D_MODEL, D_MODEL, DD, QKVW);
  transpose_bf16_kernel<<<dim3(32, 32, NLAYER), 256, 0, stream>>>(wk, WQKVT + DD, D_MODEL, D_MODEL, DD, QKVW);
  transpose_bf16_kernel<<<dim3(32, 32, NLAYER), 256, 0, stream>>>(wv, WQKVT + 2 * DD, D_MODEL, D_MODEL, DD, QKVW);
  transpose_bf16_kernel<<<dim3(32, 32, NLAYER), 256, 0, stream>>>(wo, WOT, D_MODEL, D_MODEL, DD, DD);
  transpose_bf16_kernel<<<dim3(128, 32, NLAYER), 256, 0, stream>>>(w_gate, WGU, D_MODEL, HFF, DW, GUW);
  transpose_bf16_kernel<<<dim3(128, 32, NLAYER), 256, 0, stream>>>(w_up, WGU + (size_t)HFF * D_MODEL, D_MODEL, HFF, DW, GUW);
  transpose_bf16_kernel<<<dim3(32, 128, NLAYER), 256, 0, stream>>>(w_down, WDT, HFF, D_MODEL, DW, DW);

  for (int l = 0; l < NLAYER; l++) {
    rmsnorm_kernel<<<BT, 256, 0, stream>>>(X, attn_norm + (size_t)l * D_MODEL, Hb);
    gemm_nt_kernel<1><<<(QKV_STRIDE / 128) * (BT / 128), 256, 0, stream>>>(
        Hb, WQKVT + (size_t)l * QKVW, QKVb, nullptr, BT, QKV_STRIDE, D_MODEL);
    rope_apply_kernel<<<8192, 256, 0, stream>>>(QKVb, rope_cos, rope_sin);
    attn_kernel<<<dim3(16, 32), 256, 0, stream>>>(QKVb, Ob);
    gemm_nt_kernel<2><<<(D_MODEL / 128) * (BT / 128), 256, 0, stream>>>(
        Ob, WOT + (size_t)l * DD, X, X, BT, D_MODEL, D_MODEL);

    rmsnorm_kernel<<<BT, 256, 0, stream>>>(X, mlp_norm + (size_t)l * D_MODEL, Hb);
    gemm_nt_kernel<1><<<(GU_STRIDE / 128) * (BT / 128), 256, 0, stream>>>(
        Hb, WGU + (size_t)l * GUW, GUb, nullptr, BT, GU_STRIDE, D_MODEL);
    silu_mul_kernel<<<8192, 256, 0, stream>>>(GUb, Gb);
    gemm_nt_kernel<2><<<(D_MODEL / 128) * (BT / 128), 256, 0, stream>>>(
        Gb, WDT + (size_t)l * DW, X, X, BT, D_MODEL, HFF);
  }

  rmsnorm_kernel<<<BT, 256, 0, stream>>>(X, final_norm, Hb);
  gemm_nt_kernel<0><<<(V_SIZE / 128) * (BT / 128), 256, 0, stream>>>(
      Hb, LMH, out, nullptr, BT, V_SIZE, D_MODEL);
  nll_kernel<<<BT, 256, 0, stream>>>(out, targets, NLLb);
  loss_reduce_kernel<<<1, 256, 0, stream>>>(NLLb, out + (size_t)BT * V_SIZE);
}

// Round 3
// 2307.018 us; speedup vs baseline: 1.1668x; 1.1034x over previous
//
#include <hip/hip_runtime.h>

typedef __attribute__((ext_vector_type(8))) short short8;
typedef __attribute__((ext_vector_type(4))) float f32x4;
typedef __attribute__((ext_vector_type(8))) unsigned short u16x8;
typedef unsigned short u16;

#define V_SIZE 32000
#define D_MODEL 1024
#define HFF 4096
#define NHEAD 16
#define HDIM 64
#define NLAYER 4
#define BT 4096   // B*T tokens
#define TSEQ 2048
#define QKV_STRIDE 3072
#define GU_STRIDE 8192

__device__ __forceinline__ u16 f2bf(float f) {
  union { float f; unsigned u; } v; v.f = f;
  unsigned r = v.u + 0x7fffu + ((v.u >> 16) & 1u);
  return (u16)(r >> 16);
}
__device__ __forceinline__ float bf2f(u16 h) {
  union { unsigned u; float f; } v; v.u = ((unsigned)h) << 16;
  return v.f;
}

__device__ __forceinline__ void gload_lds16(const void* g, void* l) {
  __builtin_amdgcn_global_load_lds((__attribute__((address_space(1))) void*)g,
                                   (__attribute__((address_space(3))) void*)l, 16, 0, 0);
}

// ---------------- elementwise / small kernels ----------------

__global__ void rope_table_kernel(float* __restrict__ cosb, float* __restrict__ sinb) {
  int i = blockIdx.x * 256 + threadIdx.x;       // 2048*32 = 65536 items
  int t = i >> 5, fi = i & 31;
  float freq = exp2f(-(2.0f * (float)fi / 64.0f) * log2f(10000.0f));
  float ang = (float)t * freq;
  cosb[i] = cosf(ang);
  sinb[i] = sinf(ang);
}

__global__ void convert_bf16_kernel(const float* __restrict__ src, u16* __restrict__ dst, long n8) {
  long i = (long)blockIdx.x * 256 + threadIdx.x;
  long stride = (long)gridDim.x * 256;
  for (; i < n8; i += stride) {
    const float4* s = (const float4*)(src + i * 8);
    float4 a = s[0], b = s[1];
    u16x8 r;
    r[0] = f2bf(a.x); r[1] = f2bf(a.y); r[2] = f2bf(a.z); r[3] = f2bf(a.w);
    r[4] = f2bf(b.x); r[5] = f2bf(b.y); r[6] = f2bf(b.z); r[7] = f2bf(b.w);
    *(u16x8*)(dst + i * 8) = r;
  }
}

// src [R][C] fp32 -> dst [C][R] bf16, batched over blockIdx.z
__global__ __launch_bounds__(256) void transpose_bf16_kernel(const float* __restrict__ src0,
                                                             u16* __restrict__ dst0, int R, int C,
                                                             long srcStride, long dstStride) {
  __shared__ float tile[32][33];
  const float* src = src0 + (size_t)blockIdx.z * srcStride;
  u16* dst = dst0 + (size_t)blockIdx.z * dstStride;
  int tx = threadIdx.x & 31, ty = threadIdx.x >> 5;  // 32 x 8
  int bx = blockIdx.x, by = blockIdx.y;
#pragma unroll
  for (int i = 0; i < 32; i += 8) {
    int r = by * 32 + ty + i, c = bx * 32 + tx;
    tile[ty + i][tx] = src[(size_t)r * C + c];
  }
  __syncthreads();
#pragma unroll
  for (int i = 0; i < 32; i += 8) {
    int c = bx * 32 + ty + i;   // dst row
    int r = by * 32 + tx;       // dst col
    dst[(size_t)c * R + r] = f2bf(tile[tx][ty + i]);
  }
}

__global__ void embed_gather_kernel(const int* __restrict__ idx, const float* __restrict__ embed,
                                    float* __restrict__ x) {
  int t = blockIdx.x;
  int id = idx[t];
  ((float4*)x)[(size_t)t * 256 + threadIdx.x] = ((const float4*)embed)[(size_t)id * 256 + threadIdx.x];
}

// x fp32 [4096][1024] -> h bf16, h = x * rsqrt(mean(x^2)+eps) * w
__global__ __launch_bounds__(256) void rmsnorm_kernel(const float* __restrict__ x,
                                                      const float* __restrict__ w,
                                                      u16* __restrict__ h) {
  int row = blockIdx.x;
  const float4* xr = (const float4*)(x + (size_t)row * D_MODEL);
  float4 v = xr[threadIdx.x];
  float ss = v.x * v.x + v.y * v.y + v.z * v.z + v.w * v.w;
#pragma unroll
  for (int m = 32; m > 0; m >>= 1) ss += __shfl_xor(ss, m, 64);
  __shared__ float wsum[4];
  if ((threadIdx.x & 63) == 0) wsum[threadIdx.x >> 6] = ss;
  __syncthreads();
  float tot = wsum[0] + wsum[1] + wsum[2] + wsum[3];
  float rinv = rsqrtf(tot * (1.0f / (float)D_MODEL) + 1e-6f);
  float4 wv = ((const float4*)w)[threadIdx.x];
  u16 out[4];
  out[0] = f2bf(v.x * rinv * wv.x);
  out[1] = f2bf(v.y * rinv * wv.y);
  out[2] = f2bf(v.z * rinv * wv.z);
  out[3] = f2bf(v.w * rinv * wv.w);
  u16* hp = h + (size_t)row * D_MODEL + threadIdx.x * 4;
  hp[0] = out[0]; hp[1] = out[1]; hp[2] = out[2]; hp[3] = out[3];
}

// in-place RoPE on q and k inside the fused QKV buffer (row stride 3072)
__global__ void rope_apply_kernel(u16* __restrict__ qkv,
                                  const float* __restrict__ cosb, const float* __restrict__ sinb) {
  int i = blockIdx.x * 256 + threadIdx.x;   // 4096*16*32 = 2097152
  int fi = i & 31;
  int h = (i >> 5) & 15;
  int tok = i >> 9;
  int t = tok & (TSEQ - 1);
  float c = cosb[t * 32 + fi], s = sinb[t * 32 + fi];
  size_t base = (size_t)tok * QKV_STRIDE + h * HDIM + fi;
  float q1 = bf2f(qkv[base]), q2 = bf2f(qkv[base + 32]);
  qkv[base] = f2bf(q1 * c - q2 * s);
  qkv[base + 32] = f2bf(q2 * c + q1 * s);
  size_t kb = base + D_MODEL;
  float k1 = bf2f(qkv[kb]), k2 = bf2f(qkv[kb + 32]);
  qkv[kb] = f2bf(k1 * c - k2 * s);
  qkv[kb + 32] = f2bf(k2 * c + k1 * s);
}

// gu [4096][8192] (gate | up) -> out [4096][4096] = silu(gate)*up
__global__ void silu_mul_kernel(const u16* __restrict__ gu, u16* __restrict__ out) {
  long i = (long)blockIdx.x * 256 + threadIdx.x;   // 4096*4096/8 items
  int tok = (int)(i >> 9);
  int col = ((int)i & 511) * 8;
  short8 gv = *(const short8*)(gu + (size_t)tok * GU_STRIDE + col);
  short8 uv = *(const short8*)(gu + (size_t)tok * GU_STRIDE + HFF + col);
  u16x8 r;
#pragma unroll
  for (int j = 0; j < 8; j++) {
    float gf = bf2f((u16)gv[j]);
    float uf = bf2f((u16)uv[j]);
    float sl = gf / (1.0f + expf(-gf));
    r[j] = f2bf(sl * uf);
  }
  *(u16x8*)(out + (size_t)tok * HFF + col) = r;
}

// ---------------- GEMM 256x256 8-phase (T2+T3+T4+T5), NT ----------------
// C[M,N] = A[M,K](bf16) * B[N,K](bf16)^T. 512 threads = 8 waves (2M x 4N).
// LDS 128 KiB: 2 buffers x (A[256x64] + B[256x64]) bf16, XOR-swizzled
// (linear gload_lds dest + inverse-swizzled global source + swizzled ds_read).
// EPI: 0 = store fp32 + per-(row,64col) LSE partials, 1 = store bf16.
template <int EPI>
__global__ __launch_bounds__(512, 2) void gemm256_kernel(const u16* __restrict__ A,
                                                         const u16* __restrict__ B, void* Cp,
                                                         float* __restrict__ partM,
                                                         float* __restrict__ partS,
                                                         int M, int N, int K) {
  __shared__ u16 lds[2][2][256 * 64];   // 128 KiB
  const int tid = threadIdx.x;
  const int lane = tid & 63, wid = tid >> 6;
  const int wm = wid >> 2, wn = wid & 3;          // 2 x 4 wave grid
  const int nbn = N >> 8;
  const int cpx = (int)gridDim.x >> 3;
  const int swz = ((int)blockIdx.x & 7) * cpx + ((int)blockIdx.x >> 3);
  const int bm = swz / nbn, bn = swz % nbn;
  const u16* Ab = A + (size_t)bm * 256 * K;
  const u16* Bb = B + (size_t)bn * 256 * K;

  // stage one 256x64 operand tile (4 rounds x 512thr x 16B = 32 KiB)
  auto stageA = [&](int buf, int k0) {
#pragma unroll
    for (int rnd = 0; rnd < 4; rnd++) {
      int idx16 = (rnd << 9) + tid;
      int row = idx16 >> 3, sl = idx16 & 7;
      int scol = (sl ^ (row & 7)) << 3;
      gload_lds16(Ab + (size_t)row * K + k0 + scol, &lds[buf][0][idx16 * 8]);
    }
  };
  auto stageB = [&](int buf, int k0) {
#pragma unroll
    for (int rnd = 0; rnd < 4; rnd++) {
      int idx16 = (rnd << 9) + tid;
      int row = idx16 >> 3, sl = idx16 & 7;
      int scol = (sl ^ (row & 7)) << 3;
      gload_lds16(Bb + (size_t)row * K + k0 + scol, &lds[buf][1][idx16 * 8]);
    }
  };
  // swizzled ds_read of one 16B fragment: logical (row, slot=ks*4+(lane>>4))
  auto ldsrd = [&](const u16* base, int row, int slot) -> short8 {
    return *(const short8*)(base + row * 64 + ((slot ^ (row & 7)) << 3));
  };

  f32x4 acc[8][4] = {};
  short8 af[4][2], bf0[2][2], bf1[2][2];
  const int q = lane >> 4, l15 = lane & 15;

  stageA(0, 0);
  stageB(0, 0);
  const int NT = K >> 6;
  int cur = 0;
  for (int kt = 0; kt < NT; kt++) {
    // buf[cur]'s 8 loads are the only ones outstanding (issued ~4 phases ago)
    asm volatile("s_waitcnt vmcnt(0)" ::: "memory");
    __builtin_amdgcn_s_barrier();
    const u16* LA = &lds[cur][0][0];
    const u16* LB = &lds[cur][1][0];
    // ---- P1: prefetch A(kt+1), read A-half0 + B-half0, MFMA m0 x n0
    if (kt + 1 < NT) stageA(cur ^ 1, (kt + 1) << 6);
#pragma unroll
    for (int mi = 0; mi < 4; mi++)
#pragma unroll
      for (int ks = 0; ks < 2; ks++)
        af[mi][ks] = ldsrd(LA, wm * 128 + mi * 16 + l15, ks * 4 + q);
#pragma unroll
    for (int ni = 0; ni < 2; ni++)
#pragma unroll
      for (int ks = 0; ks < 2; ks++)
        bf0[ni][ks] = ldsrd(LB, wn * 64 + ni * 16 + l15, ks * 4 + q);
    __builtin_amdgcn_s_barrier();
    __builtin_amdgcn_s_setprio(1);
#pragma unroll
    for (int mi = 0; mi < 4; mi++)
#pragma unroll
      for (int ni = 0; ni < 2; ni++)
#pragma unroll
        for (int ks = 0; ks < 2; ks++)
          acc[mi][ni] = __builtin_amdgcn_mfma_f32_16x16x32_bf16(af[mi][ks], bf0[ni][ks], acc[mi][ni], 0, 0, 0);
    __builtin_amdgcn_s_setprio(0);
    __builtin_amdgcn_s_barrier();
    // ---- P2: prefetch B(kt+1), read B-half1, MFMA m0 x n1
    if (kt + 1 < NT) stageB(cur ^ 1, (kt + 1) << 6);
#pragma unroll
    for (int ni = 0; ni < 2; ni++)
#pragma unroll
      for (int ks = 0; ks < 2; ks++)
        bf1[ni][ks] = ldsrd(LB, wn * 64 + (ni + 2) * 16 + l15, ks * 4 + q);
    __builtin_amdgcn_s_barrier();
    __builtin_amdgcn_s_setprio(1);
#pragma unroll
    for (int mi = 0; mi < 4; mi++)
#pragma unroll
      for (int ni = 0; ni < 2; ni++)
#pragma unroll
        for (int ks = 0; ks < 2; ks++)
          acc[mi][ni + 2] = __builtin_amdgcn_mfma_f32_16x16x32_bf16(af[mi][ks], bf1[ni][ks], acc[mi][ni + 2], 0, 0, 0);
    __builtin_amdgcn_s_setprio(0);
    __builtin_amdgcn_s_barrier();
    // ---- P3: read A-half1, MFMA m1 x n1
#pragma unroll
    for (int mi = 0; mi < 4; mi++)
#pragma unroll
      for (int ks = 0; ks < 2; ks++)
        af[mi][ks] = ldsrd(LA, wm * 128 + (mi + 4) * 16 + l15, ks * 4 + q);
    __builtin_amdgcn_s_barrier();
    __builtin_amdgcn_s_setprio(1);
#pragma unroll
    for (int mi = 0; mi < 4; mi++)
#pragma unroll
      for (int ni = 0; ni < 2; ni++)
#pragma unroll
        for (int ks = 0; ks < 2; ks++)
          acc[mi + 4][ni + 2] = __builtin_amdgcn_mfma_f32_16x16x32_bf16(af[mi][ks], bf1[ni][ks], acc[mi + 4][ni + 2], 0, 0, 0);
    __builtin_amdgcn_s_setprio(0);
    __builtin_amdgcn_s_barrier();
    // ---- P4: MFMA m1 x n0 (regs only)
    __builtin_amdgcn_s_setprio(1);
#pragma unroll
    for (int mi = 0; mi < 4; mi++)
#pragma unroll
      for (int ni = 0; ni < 2; ni++)
#pragma unroll
        for (int ks = 0; ks < 2; ks++)
          acc[mi + 4][ni] = __builtin_amdgcn_mfma_f32_16x16x32_bf16(af[mi][ks], bf0[ni][ks], acc[mi + 4][ni], 0, 0, 0);
    __builtin_amdgcn_s_setprio(0);
    asm volatile("" ::: "memory");
    __builtin_amdgcn_s_barrier();
    cur ^= 1;
  }

  // epilogue
  const int row0 = bm * 256 + wm * 128;
  const int col0 = bn * 256 + wn * 64;
#pragma unroll
  for (int mi = 0; mi < 8; mi++)
#pragma unroll
    for (int j = 0; j < 4; j++) {
      int r = row0 + mi * 16 + q * 4 + j;
      if (EPI == 0) {
        // LSE partial over this wave's 64 cols
        float mx = -1e30f;
#pragma unroll
        for (int ni = 0; ni < 4; ni++) mx = fmaxf(mx, acc[mi][ni][j]);
        mx = fmaxf(mx, __shfl_xor(mx, 1, 64));
        mx = fmaxf(mx, __shfl_xor(mx, 2, 64));
        mx = fmaxf(mx, __shfl_xor(mx, 4, 64));
        mx = fmaxf(mx, __shfl_xor(mx, 8, 64));
        float sm = 0.f;
#pragma unroll
        for (int ni = 0; ni < 4; ni++) sm += expf(acc[mi][ni][j] - mx);
        sm += __shfl_xor(sm, 1, 64);
        sm += __shfl_xor(sm, 2, 64);
        sm += __shfl_xor(sm, 4, 64);
        sm += __shfl_xor(sm, 8, 64);
        if (l15 == 0) {
          int nt = (N >> 6);
          partM[(size_t)r * nt + (bn << 2) + wn] = mx;
          partS[(size_t)r * nt + (bn << 2) + wn] = sm;
        }
      }
#pragma unroll
      for (int ni = 0; ni < 4; ni++) {
        int cn = col0 + ni * 16 + l15;
        size_t off = (size_t)r * N + cn;
        float vv = acc[mi][ni][j];
        if (EPI == 0) ((float*)Cp)[off] = vv;
        else ((u16*)Cp)[off] = f2bf(vv);
      }
    }
}

// ---------------- GEMM 128x128 (m97 structure) for N=1024 projections ----------------
// EPI: 2 = fp32 residual add (C = resid + acc)
template <int EPI>
__global__ __launch_bounds__(256, 2) void gemm_nt_kernel(const u16* __restrict__ A,
                                                         const u16* __restrict__ B, void* Cp,
                                                         const float* resid, int M, int N, int K) {
  __shared__ u16 As[128 * 64];
  __shared__ u16 Bs[128 * 64];
  const int tid = threadIdx.x;
  const int lane = tid & 63, wid = tid >> 6;
  const int wr = wid >> 1, wc = wid & 1;
  const int nbx = N >> 7;
  const int cpx = gridDim.x >> 3;
  const int swz = (blockIdx.x & 7) * cpx + (blockIdx.x >> 3);
  const int bm = swz / nbx, bn = swz - bm * nbx;
  const size_t abase = (size_t)bm * 128 * K;
  const size_t bbase = (size_t)bn * 128 * K;
  f32x4 acc[4][4] = {};
  for (int k0 = 0; k0 < K; k0 += 64) {
#pragma unroll
    for (int i = 0; i < 4; i++) {
      int idx8 = i * 256 + tid;
      int row = idx8 >> 3, col = (idx8 & 7) << 3;
      gload_lds16(A + abase + (size_t)row * K + k0 + col, As + idx8 * 8);
      gload_lds16(B + bbase + (size_t)row * K + k0 + col, Bs + idx8 * 8);
    }
    __syncthreads();
#pragma unroll
    for (int ks = 0; ks < 2; ks++) {
      short8 af[4], bfr[4];
      int kcol = ks * 32 + (lane >> 4) * 8;
#pragma unroll
      for (int mi = 0; mi < 4; mi++)
        af[mi] = *(const short8*)&As[(wr * 64 + mi * 16 + (lane & 15)) * 64 + kcol];
#pragma unroll
      for (int ni = 0; ni < 4; ni++)
        bfr[ni] = *(const short8*)&Bs[(wc * 64 + ni * 16 + (lane & 15)) * 64 + kcol];
#pragma unroll
      for (int mi = 0; mi < 4; mi++)
#pragma unroll
        for (int ni = 0; ni < 4; ni++)
          acc[mi][ni] = __builtin_amdgcn_mfma_f32_16x16x32_bf16(af[mi], bfr[ni], acc[mi][ni], 0, 0, 0);
    }
    __syncthreads();
  }
#pragma unroll
  for (int mi = 0; mi < 4; mi++)
#pragma unroll
    for (int ni = 0; ni < 4; ni++)
#pragma unroll
      for (int j = 0; j < 4; j++) {
        int r = bm * 128 + wr * 64 + mi * 16 + (lane >> 4) * 4 + j;
        int cn = bn * 128 + wc * 64 + ni * 16 + (lane & 15);
        size_t off = (size_t)r * N + cn;
        float vv = acc[mi][ni][j];
        if (EPI == 0) ((float*)Cp)[off] = vv;
        else if (EPI == 1) ((u16*)Cp)[off] = f2bf(vv);
        else ((float*)Cp)[off] = resid[off] + vv;
      }
}

// ---------------- flash attention ----------------
__global__ __launch_bounds__(256) void attn_kernel(const u16* __restrict__ qkv,
                                                   u16* __restrict__ o) {
  __shared__ u16 Ks[64 * 64];
  __shared__ u16 Vt[64 * 64];
  __shared__ u16 Ps[4][32 * 64];
  const u16* q = qkv;
  const u16* k = qkv + D_MODEL;
  const u16* v = qkv + 2 * D_MODEL;
  const int tid = threadIdx.x, lane = tid & 63, wid = tid >> 6;
  const int qt = blockIdx.x;
  const int bh = blockIdx.y;
  const int b = bh >> 4, h = bh & 15;
  const int tok0 = b * TSEQ;
  const int hoff = h * HDIM;
  const int qrow0 = qt * 128 + wid * 32;

  short8 aq[2][2];
#pragma unroll
  for (int mi = 0; mi < 2; mi++)
#pragma unroll
    for (int ks = 0; ks < 2; ks++) {
      int r = qrow0 + mi * 16 + (lane & 15);
      int d = ks * 32 + (lane >> 4) * 8;
      aq[mi][ks] = *(const short8*)(q + (size_t)(tok0 + r) * QKV_STRIDE + hoff + d);
    }
  f32x4 oacc[2][4] = {};
  float mrow[2][4], lrow[2][4];
#pragma unroll
  for (int mi = 0; mi < 2; mi++)
#pragma unroll
    for (int j = 0; j < 4; j++) { mrow[mi][j] = -1e30f; lrow[mi][j] = 0.f; }

  const int nkt = (qt + 1) * 2;
  for (int kt = 0; kt < nkt; kt++) {
    const int kv0 = kt * 64;
#pragma unroll
    for (int i = 0; i < 2; i++) {
      int c = tid + 256 * i;
      int row = c >> 3, col = (c & 7) * 8;
      short8 kv = *(const short8*)(k + (size_t)(tok0 + kv0 + row) * QKV_STRIDE + hoff + col);
      *(short8*)&Ks[row * 64 + (col ^ ((row & 7) << 3))] = kv;
    }
    {
      int d = tid & 63, t4 = (tid >> 6) * 8;
#pragma unroll
      for (int half = 0; half < 2; half++) {
        int t0 = t4 + half * 32;
        short8 pk;
#pragma unroll
        for (int jj = 0; jj < 8; jj++)
          pk[jj] = (short)v[(size_t)(tok0 + kv0 + t0 + jj) * QKV_STRIDE + hoff + d];
        *(short8*)&Vt[d * 64 + (t0 ^ ((d & 7) << 3))] = pk;
      }
    }
    __syncthreads();
    f32x4 sc[2][4] = {};
#pragma unroll
    for (int ks = 0; ks < 2; ks++) {
      short8 bk[4];
      int kcol = ks * 32 + (lane >> 4) * 8;
#pragma unroll
      for (int ni = 0; ni < 4; ni++) {
        int r = ni * 16 + (lane & 15);
        bk[ni] = *(const short8*)&Ks[r * 64 + (kcol ^ ((r & 7) << 3))];
      }
#pragma unroll
      for (int mi = 0; mi < 2; mi++)
#pragma unroll
        for (int ni = 0; ni < 4; ni++)
          sc[mi][ni] = __builtin_amdgcn_mfma_f32_16x16x32_bf16(aq[mi][ks], bk[ni], sc[mi][ni], 0, 0, 0);
    }
    float pm[2][4];
#pragma unroll
    for (int mi = 0; mi < 2; mi++)
#pragma unroll
      for (int j = 0; j < 4; j++) pm[mi][j] = -1e30f;
#pragma unroll
    for (int mi = 0; mi < 2; mi++)
#pragma unroll
      for (int ni = 0; ni < 4; ni++)
#pragma unroll
        for (int j = 0; j < 4; j++) {
          int rq = qrow0 + mi * 16 + (lane >> 4) * 4 + j;
          int ck = kv0 + ni * 16 + (lane & 15);
          float s = sc[mi][ni][j] * 0.125f;
          if (ck > rq) s = -1e30f;
          sc[mi][ni][j] = s;
          pm[mi][j] = fmaxf(pm[mi][j], s);
        }
#pragma unroll
    for (int mi = 0; mi < 2; mi++)
#pragma unroll
      for (int j = 0; j < 4; j++) {
        float t = pm[mi][j];
        t = fmaxf(t, __shfl_xor(t, 1, 64));
        t = fmaxf(t, __shfl_xor(t, 2, 64));
        t = fmaxf(t, __shfl_xor(t, 4, 64));
        t = fmaxf(t, __shfl_xor(t, 8, 64));
        pm[mi][j] = t;
      }
#pragma unroll
    for (int mi = 0; mi < 2; mi++)
#pragma unroll
      for (int j = 0; j < 4; j++) {
        float mn = fmaxf(mrow[mi][j], pm[mi][j]);
        float fac = expf(mrow[mi][j] - mn);
        lrow[mi][j] *= fac;
#pragma unroll
        for (int df = 0; df < 4; df++) oacc[mi][df][j] *= fac;
        mrow[mi][j] = mn;
      }
    float psum[2][4] = {};
#pragma unroll
    for (int mi = 0; mi < 2; mi++)
#pragma unroll
      for (int ni = 0; ni < 4; ni++)
#pragma unroll
        for (int j = 0; j < 4; j++) {
          float p = expf(sc[mi][ni][j] - mrow[mi][j]);
          psum[mi][j] += p;
          int r32 = mi * 16 + (lane >> 4) * 4 + j;
          int cc = ni * 16 + (lane & 15);
          Ps[wid][r32 * 64 + (cc ^ ((r32 & 7) << 3))] = f2bf(p);
        }
#pragma unroll
    for (int mi = 0; mi < 2; mi++)
#pragma unroll
      for (int j = 0; j < 4; j++) {
        float t = psum[mi][j];
        t += __shfl_xor(t, 1, 64);
        t += __shfl_xor(t, 2, 64);
        t += __shfl_xor(t, 4, 64);
        t += __shfl_xor(t, 8, 64);
        lrow[mi][j] += t;
      }
#pragma unroll
    for (int kf = 0; kf < 2; kf++) {
      short8 pa[2], bv[4];
      int kcol = kf * 32 + (lane >> 4) * 8;
#pragma unroll
      for (int mi = 0; mi < 2; mi++) {
        int r = mi * 16 + (lane & 15);
        pa[mi] = *(const short8*)&Ps[wid][r * 64 + (kcol ^ ((r & 7) << 3))];
      }
#pragma unroll
      for (int df = 0; df < 4; df++) {
        int r = df * 16 + (lane & 15);
        bv[df] = *(const short8*)&Vt[r * 64 + (kcol ^ ((r & 7) << 3))];
      }
#pragma unroll
      for (int mi = 0; mi < 2; mi++)
#pragma unroll
        for (int df = 0; df < 4; df++)
          oacc[mi][df] = __builtin_amdgcn_mfma_f32_16x16x32_bf16(pa[mi], bv[df], oacc[mi][df], 0, 0, 0);
    }
    __syncthreads();
  }
#pragma unroll
  for (int mi = 0; mi < 2; mi++)
#pragma unroll
    for (int df = 0; df < 4; df++)
#pragma unroll
      for (int j = 0; j < 4; j++) {
        int r = qrow0 + mi * 16 + (lane >> 4) * 4 + j;
        int d = df * 16 + (lane & 15);
        float val = oacc[mi][df][j] / lrow[mi][j];
        o[(size_t)(tok0 + r) * D_MODEL + hoff + d] = f2bf(val);
      }
}

// ---------------- loss ----------------

// combine per-64col partials (500 per token) + gather target logit
__global__ void nll_finalize_kernel(const float* __restrict__ partM, const float* __restrict__ partS,
                                    const float* __restrict__ logits, const int* __restrict__ targets,
                                    float* __restrict__ nll) {
  int tok = blockIdx.x;
  int lane = threadIdx.x;    // 64
  const int NTL = V_SIZE >> 6;  // 500
  float m = -1e30f, s = 0.f;
  for (int i = lane; i < NTL; i += 64) {
    float m2 = partM[(size_t)tok * NTL + i];
    float s2 = partS[(size_t)tok * NTL + i];
    float nm = fmaxf(m, m2);
    s = s * expf(m - nm) + s2 * expf(m2 - nm);
    m = nm;
  }
#pragma unroll
  for (int mask = 1; mask < 64; mask <<= 1) {
    float m2 = __shfl_xor(m, mask, 64);
    float s2 = __shfl_xor(s, mask, 64);
    float nm = fmaxf(m, m2);
    s = s * expf(m - nm) + s2 * expf(m2 - nm);
    m = nm;
  }
  if (lane == 0)
    nll[tok] = m + logf(s) - logits[(size_t)tok * V_SIZE + targets[tok]];
}

__global__ void loss_reduce_kernel(const float* __restrict__ nll, float* __restrict__ out) {
  float s = 0.f;
  for (int i = threadIdx.x; i < BT; i += 256) s += nll[i];
#pragma unroll
  for (int mask = 1; mask < 64; mask <<= 1) s += __shfl_xor(s, mask, 64);
  __shared__ float sm[4];
  if ((threadIdx.x & 63) == 0) sm[threadIdx.x >> 6] = s;
  __syncthreads();
  if (threadIdx.x == 0) out[0] = (sm[0] + sm[1] + sm[2] + sm[3]) / (float)BT;
}

// ---------------- host launcher ----------------

extern "C" void kernel_launch(void* const* d_in, const int* in_sizes, int n_in,
                              void* d_out, int out_size, void* d_ws, size_t ws_size,
                              hipStream_t stream) {
  const int* idx = (const int*)d_in[0];
  const int* targets = (const int*)d_in[1];
  const float* embed = (const float*)d_in[2];
  const float* wq = (const float*)d_in[3];
  const float* wk = (const float*)d_in[4];
  const float* wv = (const float*)d_in[5];
  const float* wo = (const float*)d_in[6];
  const float* w_gate = (const float*)d_in[7];
  const float* w_up = (const float*)d_in[8];
  const float* w_down = (const float*)d_in[9];
  const float* attn_norm = (const float*)d_in[10];
  const float* mlp_norm = (const float*)d_in[11];
  const float* final_norm = (const float*)d_in[12];
  const float* lm_head = (const float*)d_in[13];
  float* out = (float*)d_out;

  char* ws = (char*)d_ws;
  size_t off = 0;
  auto alloc = [&](size_t bytes) {
    void* p = ws + off;
    off += (bytes + 255) & ~(size_t)255;
    return p;
  };
  const size_t DD = (size_t)D_MODEL * D_MODEL;
  float* rope_cos = (float*)alloc((size_t)TSEQ * 32 * 4);
  float* rope_sin = (float*)alloc((size_t)TSEQ * 32 * 4);
  float* X = (float*)alloc((size_t)BT * D_MODEL * 4);
  u16* Hb = (u16*)alloc((size_t)BT * D_MODEL * 2);
  u16* QKVb = (u16*)alloc((size_t)BT * QKV_STRIDE * 2);
  u16* Ob = (u16*)alloc((size_t)BT * D_MODEL * 2);
  u16* GUb = (u16*)alloc((size_t)BT * GU_STRIDE * 2);
  u16* Gb = (u16*)alloc((size_t)BT * HFF * 2);
  u16* WQKVT = (u16*)alloc((size_t)NLAYER * QKV_STRIDE * D_MODEL * 2);
  u16* WOT = (u16*)alloc((size_t)NLAYER * DD * 2);
  u16* WGU = (u16*)alloc((size_t)NLAYER * GU_STRIDE * D_MODEL * 2);
  u16* WDT = (u16*)alloc((size_t)NLAYER * D_MODEL * HFF * 2);
  u16* LMH = (u16*)alloc((size_t)V_SIZE * D_MODEL * 2);
  float* NLLb = (float*)alloc((size_t)BT * 4);
  float* PartM = (float*)alloc((size_t)BT * (V_SIZE >> 6) * 4);
  float* PartS = (float*)alloc((size_t)BT * (V_SIZE >> 6) * 4);

  rope_table_kernel<<<256, 256, 0, stream>>>(rope_cos, rope_sin);
  convert_bf16_kernel<<<4096, 256, 0, stream>>>(lm_head, LMH, (long)V_SIZE * D_MODEL / 8);
  embed_gather_kernel<<<BT, 256, 0, stream>>>(idx, embed, X);

  const long QKVW = (long)QKV_STRIDE * D_MODEL;
  const long GUW = (long)GU_STRIDE * D_MODEL;
  const long DW = (long)D_MODEL * HFF;
  transpose_bf16_kernel<<<dim3(32, 32, NLAYER), 256, 0, stream>>>(wq, WQKVT, D_MODEL, D_MODEL, DD, QKVW);
  transpose_bf16_kernel<<<dim3(32, 32, NLAYER), 256, 0, stream>>>(wk, WQKVT + DD, D_MODEL, D_MODEL, DD, QKVW);
  transpose_bf16_kernel<<<dim3(32, 32, NLAYER), 256, 0, stream>>>(wv, WQKVT + 2 * DD, D_MODEL, D_MODEL, DD, QKVW);
  transpose_bf16_kernel<<<dim3(32, 32, NLAYER), 256, 0, stream>>>(wo, WOT, D_MODEL, D_MODEL, DD, DD);
  transpose_bf16_kernel<<<dim3(128, 32, NLAYER), 256, 0, stream>>>(w_gate, WGU, D_MODEL, HFF, DW, GUW);
  transpose_bf16_kernel<<<dim3(128, 32, NLAYER), 256, 0, stream>>>(w_up, WGU + (size_t)HFF * D_MODEL, D_MODEL, HFF, DW, GUW);
  transpose_bf16_kernel<<<dim3(32, 128, NLAYER), 256, 0, stream>>>(w_down, WDT, HFF, D_MODEL, DW, DW);

  for (int l = 0; l < NLAYER; l++) {
    rmsnorm_kernel<<<BT, 256, 0, stream>>>(X, attn_norm + (size_t)l * D_MODEL, Hb);
    gemm256_kernel<1><<<(QKV_STRIDE / 256) * (BT / 256), 512, 0, stream>>>(
        Hb, WQKVT + (size_t)l * QKVW, QKVb, nullptr, nullptr, BT, QKV_STRIDE, D_MODEL);
    rope_apply_kernel<<<8192, 256, 0, stream>>>(QKVb, rope_cos, rope_sin);
    attn_kernel<<<dim3(16, 32), 256, 0, stream>>>(QKVb, Ob);
    gemm_nt_kernel<2><<<(D_MODEL / 128) * (BT / 128), 256, 0, stream>>>(
        Ob, WOT + (size_t)l * DD, X, X, BT, D_MODEL, D_MODEL);

    rmsnorm_kernel<<<BT, 256, 0, stream>>>(X, mlp_norm + (size_t)l * D_MODEL, Hb);
    gemm256_kernel<1><<<(GU_STRIDE / 256) * (BT / 256), 512, 0, stream>>>(
        Hb, WGU + (size_t)l * GUW, GUb, nullptr, nullptr, BT, GU_STRIDE, D_MODEL);
    silu_mul_kernel<<<8192, 256, 0, stream>>>(GUb, Gb);
    gemm_nt_kernel<2><<<(D_MODEL / 128) * (BT / 128), 256, 0, stream>>>(
        Gb, WDT + (size_t)l * DW, X, X, BT, D_MODEL, HFF);
  }

  rmsnorm_kernel<<<BT, 256, 0, stream>>>(X, final_norm, Hb);
  gemm256_kernel<0><<<(V_SIZE / 256) * (BT / 256), 512, 0, stream>>>(
      Hb, LMH, out, PartM, PartS, BT, V_SIZE, D_MODEL);
  nll_finalize_kernel<<<BT, 64, 0, stream>>>(PartM, PartS, out, targets, NLLb);
  loss_reduce_kernel<<<1, 256, 0, stream>>>(NLLb, out + (size_t)BT * V_SIZE);
}